// Round 4
// baseline (288.598 us; speedup 1.0000x reference)
//
#include <hip/hip_runtime.h>

// GCN layer: out = relu(x @ W_self^T + b_self + segment_mean(x[src], dst) @ W_neigh^T)
// N = 100000 nodes, D = 64, E = 1.25M edges.
//
// R3 restructure kept: mean-then-matmul == matmul-then-mean (linearity).
// y = x@Ws^T + b (fp32) and z = x@Wn^T (bf16) are computed FIRST; the edge
// gather averages z rows and finishes out = relu(y + mean).
//
// R4 restructure: exact counting-sort CSR replaces the two-stage binning
// (radix scatter into ebuf + in-LDS bucket sort). Degree histogram + per-bucket
// scan gives every node its exact col[] range; a one-thread-per-edge scatter
// then places each src directly at its final position. Deletes the ebuf plane,
// the 306x196 contended cursor claims, the 60K partial-line flush segments,
// and the duplicate histogram+scan in sb_csr. col layout (node-grouped within
// fixed per-bucket windows) is identical to before, so the gather is untouched.
//
// Pipeline (memset + 4 kernels):
//   memset       : deg[N] = 0 (400 KB).
//   k1_main      : block-role split. Blocks [0,HISTB): degree histogram
//                  (1.25M global atomicAdds over 100K addresses, ~12.5
//                  hits/address -> low contention). Blocks [HISTB,+GB):
//                  dual-output MFMA GEMM straight from fp32 x: y=x@Ws^T+b
//                  (fp32), z=x@Wn^T (bf16). Atomic role overlaps MFMA role.
//   bucket_scan  : 196 blocks x 512 thr: exclusive scan of degrees within the
//                  bucket -> rowse (start,count) + cur (scatter cursor).
//                  Per-bucket fixed windows (CAPE) -> no cross-bucket scan.
//   edge_scatter : one thread per edge: col[atomicAdd(&cur[dst],1)] = src.
//                  Scattered 4B writes into 5.6 MB; byte-enable merge at
//                  L2/L3 handles cross-XCD partial lines.
//   gather_final : one wave per node on bf16 z rows (128B): 8 edges per
//                  dwordx4, 2 loads in flight, fp32 accumulate, cross-oct
//                  shuffle reduce; epilogue reads y row, out=relu(y+mean).

#define BKSH 9                // log2(nodes per bucket)
#define BKN 512               // nodes per bucket
#define CAPE 7168             // col capacity per bucket (mean 6400, +9.6 sigma)
#define HISTB 512             // histogram-role blocks in k1_main

typedef __attribute__((ext_vector_type(8))) short short8;
typedef __attribute__((ext_vector_type(4))) float floatx4;

// fp32 -> bf16 round-to-nearest-even, branch-free.
static __device__ inline unsigned short f2bf(float f) {
  union { float f; unsigned int u; } v;
  v.f = f;
  unsigned int r = v.u + 0x7FFFu + ((v.u >> 16) & 1u);
  return (unsigned short)(r >> 16);
}

static __device__ inline short8 pack8(float4 a, float4 b) {
  short8 s;
  s[0] = (short)f2bf(a.x); s[1] = (short)f2bf(a.y);
  s[2] = (short)f2bf(a.z); s[3] = (short)f2bf(a.w);
  s[4] = (short)f2bf(b.x); s[5] = (short)f2bf(b.y);
  s[6] = (short)f2bf(b.z); s[7] = (short)f2bf(b.w);
  return s;
}

// unpack 8 bf16 (4 dwords) and accumulate into 8 fp32.
static __device__ inline void add8(float* a, short8 sv) {
  union { short8 s; unsigned int u[4]; } c; c.s = sv;
#pragma unroll
  for (int i = 0; i < 4; ++i) {
    a[2 * i]     += __uint_as_float(c.u[i] << 16);
    a[2 * i + 1] += __uint_as_float(c.u[i] & 0xFFFF0000u);
  }
}

// Fused: degree histogram (blocks < HISTB) | dual-GEMM y,z from fp32 x.
__global__ __launch_bounds__(256) void k1_main(
    const float* __restrict__ x,
    const float* __restrict__ Wself, const float* __restrict__ bself,
    const float* __restrict__ Wneigh,
    float* __restrict__ yb, unsigned short* __restrict__ zb,
    const int* __restrict__ dst, int* __restrict__ deg,
    int E, int N) {
  int t = threadIdx.x;
  int bid = blockIdx.x;

  if (bid < HISTB) {
    // ---- histogram role: deg[dst]++ over all edges, grid-stride ----
    int stride = HISTB * 256;
    for (int e = bid * 256 + t; e < E; e += stride)
      atomicAdd(&deg[dst[e]], 1);
    return;
  }

  // ---- GEMM role: y = x@Ws^T + b (fp32), z = x@Wn^T (bf16) ----
  int lane = t & 63;
  int w = t >> 6;
  int tb = (bid - HISTB) * 64 + w * 16;
  int m = lane & 15, q = lane >> 4;

  long long rowA = (long long)min(tb + m, N - 1) * 64;
  short8 ax[2];
#pragma unroll
  for (int ks = 0; ks < 2; ++ks) {
    const float* xr = &x[rowA + ks * 32 + q * 8];
    ax[ks] = pack8(*(const float4*)xr, *(const float4*)(xr + 4));
  }

#pragma unroll
  for (int nt = 0; nt < 4; ++nt) {
    int ob = nt * 16;
    long long rowB = (long long)(ob + m) * 64;
    floatx4 accs = {0.f, 0.f, 0.f, 0.f};
    floatx4 accn = {0.f, 0.f, 0.f, 0.f};
#pragma unroll
    for (int ks = 0; ks < 2; ++ks) {
      const float* pw = &Wself[rowB + ks * 32 + q * 8];
      short8 bs = pack8(*(const float4*)pw, *(const float4*)(pw + 4));
      accs = __builtin_amdgcn_mfma_f32_16x16x32_bf16(ax[ks], bs, accs, 0, 0, 0);
      const float* pn = &Wneigh[rowB + ks * 32 + q * 8];
      short8 bn = pack8(*(const float4*)pn, *(const float4*)(pn + 4));
      accn = __builtin_amdgcn_mfma_f32_16x16x32_bf16(ax[ks], bn, accn, 0, 0, 0);
    }
    float bias = bself[ob + m];
#pragma unroll
    for (int r = 0; r < 4; ++r) {
      int node = tb + q * 4 + r;
      if (node < N) {
        yb[(long long)node * 64 + ob + m] = accs[r] + bias;
        zb[(long long)node * 64 + ob + m] = f2bf(accn[r]);
      }
    }
  }
}

// One 512-thread block per 512-node bucket: exclusive scan of degrees ->
// rowse (start,count) and cur (scatter cursor). Fixed per-bucket windows
// (b*CAPE) in col, so no cross-bucket dependency.
__global__ __launch_bounds__(512) void bucket_scan(const int* __restrict__ deg,
                                                   int2* __restrict__ rowse,
                                                   int* __restrict__ cur, int N) {
  __shared__ int wsum[8];
  int b = blockIdx.x, t = threadIdx.x;
  int node = (b << BKSH) + t;
  int v = (node < N) ? deg[node] : 0;

  int lane = t & 63, w = t >> 6;
  int inc = v;
#pragma unroll
  for (int o = 1; o < 64; o <<= 1) {
    int u = __shfl_up(inc, o, 64);
    if (lane >= o) inc += u;
  }
  if (lane == 63) wsum[w] = inc;
  __syncthreads();
  if (t < 8) {
    int s0 = wsum[t], incw = s0;
#pragma unroll
    for (int o = 1; o < 8; o <<= 1) {
      int u = __shfl_up(incw, o, 64);
      if (t >= o) incw += u;
    }
    wsum[t] = incw - s0;
  }
  __syncthreads();
  int ex = wsum[w] + inc - v;
  int start = b * CAPE + ex;
  if (node < N) {
    rowse[node] = make_int2(start, v);
    cur[node] = start;
  }
}

// One thread per edge: place src at its exact CSR position.
__global__ __launch_bounds__(256) void edge_scatter(const int* __restrict__ src,
                                                    const int* __restrict__ dst,
                                                    int* __restrict__ cur,
                                                    int* __restrict__ col, int E) {
  int e = blockIdx.x * 256 + threadIdx.x;
  if (e < E) {
    int p = atomicAdd(&cur[dst[e]], 1);
    col[p] = src[e];
  }
}

// One wave per node on bf16 z rows (128B). Oct o handles edges j = s+o,
// s+o+8...; one dwordx4 covers 8 edges (1KB). 2 loads in flight (clamped 2nd
// index hits the same line -> free). fp32 accumulate, 3-round cross-oct
// shuffle reduce; epilogue: out = relu(y + mean) written fp32 (full row
// covered contiguously by 8 lanes x 32B).
__global__ __launch_bounds__(256) void gather_final(
    const unsigned short* __restrict__ zb,
    const int2* __restrict__ rowse,
    const int* __restrict__ col,
    const float* __restrict__ yb,
    float* __restrict__ out, int N) {
  int gid = blockIdx.x * 256 + threadIdx.x;
  int node = gid >> 6;
  if (node >= N) return;
  int lane = threadIdx.x & 63;
  int o = lane >> 3, d = lane & 7;
  int2 se = rowse[node];
  int s = se.x, c = se.y, e = s + c;

  float a[8] = {0.f, 0.f, 0.f, 0.f, 0.f, 0.f, 0.f, 0.f};
  float b2[8] = {0.f, 0.f, 0.f, 0.f, 0.f, 0.f, 0.f, 0.f};
  for (int j = s + o; j < e; j += 16) {
    int c0 = col[j];
    bool h2 = (j + 8) < e;
    int c1 = h2 ? col[j + 8] : c0;  // clamp: redundant load hits same line
    short8 v0 = *(const short8*)&zb[(long long)c0 * 64 + d * 8];
    short8 v1 = *(const short8*)&zb[(long long)c1 * 64 + d * 8];
    add8(a, v0);
    if (h2) add8(b2, v1);
  }
#pragma unroll
  for (int k = 0; k < 8; ++k) a[k] += b2[k];

#pragma unroll
  for (int m = 8; m <= 32; m <<= 1) {
#pragma unroll
    for (int k = 0; k < 8; ++k) a[k] += __shfl_xor(a[k], m, 64);
  }

  if (o == 0) {
    float inv = 1.0f / fmaxf((float)c, 1.0f);
    long long ro = (long long)node * 64 + d * 8;
    float4 y0 = *(const float4*)&yb[ro];
    float4 y1 = *(const float4*)&yb[ro + 4];
    float4 r0, r1;
    r0.x = fmaxf(y0.x + a[0] * inv, 0.f);
    r0.y = fmaxf(y0.y + a[1] * inv, 0.f);
    r0.z = fmaxf(y0.z + a[2] * inv, 0.f);
    r0.w = fmaxf(y0.w + a[3] * inv, 0.f);
    r1.x = fmaxf(y1.x + a[4] * inv, 0.f);
    r1.y = fmaxf(y1.y + a[5] * inv, 0.f);
    r1.z = fmaxf(y1.z + a[6] * inv, 0.f);
    r1.w = fmaxf(y1.w + a[7] * inv, 0.f);
    *(float4*)&out[ro] = r0;
    *(float4*)&out[ro + 4] = r1;
  }
}

extern "C" void kernel_launch(void* const* d_in, const int* in_sizes, int n_in,
                              void* d_out, int out_size, void* d_ws, size_t ws_size,
                              hipStream_t stream) {
  const float* x      = (const float*)d_in[0];
  const int*   eidx   = (const int*)d_in[1];
  const float* Wself  = (const float*)d_in[2];
  const float* bself  = (const float*)d_in[3];
  const float* Wneigh = (const float*)d_in[4];
  float* out = (float*)d_out;

  const int N = in_sizes[0] / 64;
  const int E = in_sizes[1] / 2;
  const int* src = eidx;      // edge_index row 0
  const int* dst = eidx + E;  // edge_index row 1
  const int NB = (N + BKN - 1) / BKN;  // 196 buckets of 512 nodes

  // ws layout: yb fp32[N*64] | zb bf16[N*64] | deg[N] | cur[N]
  //            | rowse int2[N] | col[NB*CAPE]   (~46 MB)
  float* yb = (float*)d_ws;
  unsigned short* zb = (unsigned short*)(yb + (size_t)N * 64);
  int* deg    = (int*)(zb + (size_t)N * 64);
  int* cur    = deg + N;
  int2* rowse = (int2*)(cur + N);
  int* col    = (int*)(rowse + N);

  hipMemsetAsync(deg, 0, (size_t)N * sizeof(int), stream);

  const int GB = (N + 63) / 64;  // 1563 GEMM blocks
  k1_main<<<HISTB + GB, 256, 0, stream>>>(x, Wself, bself, Wneigh, yb, zb,
                                          dst, deg, E, N);
  bucket_scan<<<NB, BKN, 0, stream>>>(deg, rowse, cur, N);
  edge_scatter<<<(E + 255) / 256, 256, 0, stream>>>(src, dst, cur, col, E);
  gather_final<<<(int)(((long long)N * 64 + 255) / 256), 256, 0, stream>>>(
      zb, rowse, col, yb, out, N);
}

// Round 7
// 158.555 us; speedup vs baseline: 1.8202x; 1.8202x over previous
//
#include <hip/hip_runtime.h>

// GCN layer: out = relu(x @ W_self^T + b_self + segment_mean(x[src], dst) @ W_neigh^T)
// N = 100000 nodes, D = 64, E = 1.25M edges.
//
// R3 structure (163 µs): mean-then-matmul == matmul-then-mean (linearity).
// y = x@Ws^T + b (fp32) and z = x@Wn^T (bf16) computed FIRST; edge gather
// averages z rows and finishes out = relu(y + mean).
// R4 (per-edge scattered global writes) REVERTED: 16x write amplification.
//
// R6 FAILED correctness (absmax 0.328): the shfl-gather loop had a
// lane-DIVERGENT trip count (k = o; k < c; k += 16). Lanes exit early, and
// __shfl from a lane that has exited a divergent loop is UNDEFINED on gfx950
// (ds_bpermute from inactive lane). For deg in 17..18 / 33..36 / 49..54 the
// source lane was inactive -> garbage neighbor row (~8% of nodes).
// R7 fix: wave-UNIFORM trip count (kb = 0; kb < c; kb += 16, c uniform) with
// predicated accumulates -- all 64 lanes stay active at every shfl.
//
// Deltas vs R3 otherwise unchanged:
//   * scatter role: per-wave privatized LDS histograms + exact per-wave
//     sub-cursors (contention /4 on both atomic passes).
//   * gather: whole adjacency loaded as ONE coalesced col line + __shfl
//     distribution (col->z two-deep global chain becomes shfl->z), y-row
//     prefetch hoisted above the edge loop. Fallback path for deg > 64.
//
// Pipeline (memset + 3 kernels):
//   memset      : cursor[256] = 0.
//   k1_main     : blocks [0,SCB): LDS-staged radix scatter into 196 buckets
//                 of 512 dst-nodes (contiguous-run claim via global cursor
//                 atomics, full-line ebuf writes). Blocks [SCB,+GB):
//                 dual-output MFMA GEMM straight from fp32 x.
//   sb_csr      : one 512-thread block per bucket. Window read ONCE into
//                 registers, in-LDS node-sort, coalesced flush to col.
//                 NOTE: LDS *int* atomics only — LDS fp32 atomicAdd is a CAS
//                 loop on gfx950 and serializes (r3/r11: ~500 µs disasters).
//   gather_final: one wave per node on bf16 z rows (128B), shfl-distributed
//                 edge indices (uniform trip count), 2 z-loads in flight,
//                 cross-oct shuffle reduce; epilogue out = relu(y + mean).

#define BKSH 9                // log2(nodes per bucket)
#define BKN 512               // nodes per bucket
#define NBMAX 256             // >= NB = 196
#define CAPE 7168             // edge capacity per bucket (mean 6400, +9.6 sigma)
#define WPT (CAPE / BKN)      // window entries per thread in sb_csr = 14
#define CHUNK 4096            // edges per scatter block
#define EPT (CHUNK / 256)     // edges per thread in scatter = 16

typedef __attribute__((ext_vector_type(8))) short short8;
typedef __attribute__((ext_vector_type(4))) float floatx4;

// fp32 -> bf16 round-to-nearest-even, branch-free.
static __device__ inline unsigned short f2bf(float f) {
  union { float f; unsigned int u; } v;
  v.f = f;
  unsigned int r = v.u + 0x7FFFu + ((v.u >> 16) & 1u);
  return (unsigned short)(r >> 16);
}

static __device__ inline short8 pack8(float4 a, float4 b) {
  short8 s;
  s[0] = (short)f2bf(a.x); s[1] = (short)f2bf(a.y);
  s[2] = (short)f2bf(a.z); s[3] = (short)f2bf(a.w);
  s[4] = (short)f2bf(b.x); s[5] = (short)f2bf(b.y);
  s[6] = (short)f2bf(b.z); s[7] = (short)f2bf(b.w);
  return s;
}

// unpack 8 bf16 (4 dwords) and accumulate into 8 fp32.
static __device__ inline void add8(float* a, short8 sv) {
  union { short8 s; unsigned int u[4]; } c; c.s = sv;
#pragma unroll
  for (int i = 0; i < 4; ++i) {
    a[2 * i]     += __uint_as_float(c.u[i] << 16);
    a[2 * i + 1] += __uint_as_float(c.u[i] & 0xFFFF0000u);
  }
}

// Fused: edge radix-scatter (blocks < SCB) | dual-GEMM y,z from fp32 x.
__global__ __launch_bounds__(256) void k1_main(
    const float* __restrict__ x,
    const float* __restrict__ Wself, const float* __restrict__ bself,
    const float* __restrict__ Wneigh,
    float* __restrict__ yb, unsigned short* __restrict__ zb,
    const int* __restrict__ src, const int* __restrict__ dst,
    int* __restrict__ cursor, int* __restrict__ ebuf,
    int E, int N, int NB, int SCB) {
  __shared__ int hw[4][NBMAX];                 // per-wave counts -> cursors
  __shared__ int tot[NBMAX], loff[NBMAX], gbase[NBMAX];
  __shared__ int sbuf[CHUNK];
  int t = threadIdx.x;
  int bid = blockIdx.x;

  if (bid >= SCB) {
    // ---- GEMM role: y = x@Ws^T + b (fp32), z = x@Wn^T (bf16) ----
    int lane = t & 63;
    int w = t >> 6;
    int tb = (bid - SCB) * 64 + w * 16;
    int m = lane & 15, q = lane >> 4;

    long long rowA = (long long)min(tb + m, N - 1) * 64;
    short8 ax[2];
#pragma unroll
    for (int ks = 0; ks < 2; ++ks) {
      const float* xr = &x[rowA + ks * 32 + q * 8];
      ax[ks] = pack8(*(const float4*)xr, *(const float4*)(xr + 4));
    }

#pragma unroll
    for (int nt = 0; nt < 4; ++nt) {
      int ob = nt * 16;
      long long rowB = (long long)(ob + m) * 64;
      floatx4 accs = {0.f, 0.f, 0.f, 0.f};
      floatx4 accn = {0.f, 0.f, 0.f, 0.f};
#pragma unroll
      for (int ks = 0; ks < 2; ++ks) {
        const float* pw = &Wself[rowB + ks * 32 + q * 8];
        short8 bs = pack8(*(const float4*)pw, *(const float4*)(pw + 4));
        accs = __builtin_amdgcn_mfma_f32_16x16x32_bf16(ax[ks], bs, accs, 0, 0, 0);
        const float* pn = &Wneigh[rowB + ks * 32 + q * 8];
        short8 bn = pack8(*(const float4*)pn, *(const float4*)(pn + 4));
        accn = __builtin_amdgcn_mfma_f32_16x16x32_bf16(ax[ks], bn, accn, 0, 0, 0);
      }
      float bias = bself[ob + m];
#pragma unroll
      for (int r = 0; r < 4; ++r) {
        int node = tb + q * 4 + r;
        if (node < N) {
          yb[(long long)node * 64 + ob + m] = accs[r] + bias;
          zb[(long long)node * 64 + ob + m] = f2bf(accn[r]);
        }
      }
    }
    return;
  }

  // ---- scatter role ----
  int w = t >> 6, lane = t & 63;
  for (int i = t; i < 4 * NBMAX; i += 256) ((int*)hw)[i] = 0;
  __syncthreads();

  int base = bid * CHUNK;
  int myd[EPT], mys[EPT];
#pragma unroll
  for (int i = 0; i < EPT; ++i) {
    int e = base + t + 256 * i;  // coalesced
    if (e < E) {
      myd[i] = dst[e];
      mys[i] = src[e];
      atomicAdd(&hw[w][myd[i] >> BKSH], 1);  // per-wave: contention /4
    } else myd[i] = -1;
  }
  __syncthreads();

  if (t < 64) {  // wave 0: totals, exclusive scan, per-wave sub-cursors
    int i0 = 4 * t;
    int h0[4], h1[4], h2[4], c[4];
#pragma unroll
    for (int k = 0; k < 4; ++k) {
      int b = i0 + k;
      h0[k] = hw[0][b]; h1[k] = hw[1][b]; h2[k] = hw[2][b];
      c[k] = h0[k] + h1[k] + h2[k] + hw[3][b];
    }
    int s4 = c[0] + c[1] + c[2] + c[3], inc = s4;
#pragma unroll
    for (int off = 1; off < 64; off <<= 1) {
      int u = __shfl_up(inc, off, 64);
      if (t >= off) inc += u;
    }
    int ex = inc - s4;
    int l[4];
    l[0] = ex; l[1] = ex + c[0]; l[2] = l[1] + c[1]; l[3] = l[2] + c[2];
#pragma unroll
    for (int k = 0; k < 4; ++k) {
      int b = i0 + k;
      loff[b] = l[k]; tot[b] = c[k];
      hw[0][b] = l[k];
      hw[1][b] = l[k] + h0[k];
      hw[2][b] = l[k] + h0[k] + h1[k];
      hw[3][b] = l[k] + h0[k] + h1[k] + h2[k];
    }
  }
  __syncthreads();

  if (t < NB) {
    if (tot[t] > 0) gbase[t] = t * CAPE + atomicAdd(&cursor[t], tot[t]);  // claim
  }
  __syncthreads();

#pragma unroll
  for (int i = 0; i < EPT; ++i) {
    if (myd[i] >= 0) {
      int b = myd[i] >> BKSH;
      int p = atomicAdd(&hw[w][b], 1);       // exact position, intra-wave only
      sbuf[p] = mys[i] | ((myd[i] & (BKN - 1)) << 17);  // src < 2^17
    }
  }
  __syncthreads();

  for (int b = w; b < NB; b += 4) {
    int c = tot[b], lo = loff[b], go = gbase[b];
    for (int j = lane; j < c; j += 64)
      ebuf[go + j] = sbuf[lo + j];
  }
}

// One 512-thread block per 512-node bucket (196 blocks). Window read ONCE
// from global into registers; count -> block scan -> in-LDS node-sort ->
// coalesced flush. cnt[] doubles as scatter cursor (seeded with exclusive
// prefix), so the atomicAdd result IS the final sorted position.
__global__ __launch_bounds__(512) void sb_csr(const int* __restrict__ cursor,
                                              const int* __restrict__ ebuf,
                                              int* __restrict__ col,
                                              int2* __restrict__ rowse, int N) {
  __shared__ int sbuf[CAPE];   // 28672 B
  __shared__ int cnt[BKN];     //  2048 B
  __shared__ int wsum[8];      // total ~30.8 KB
  int b = blockIdx.x, t = threadIdx.x;
  int s = b * CAPE;
  int n = cursor[b];
  int e = s + n;

  // stage window into registers (static indices -> stays in VGPRs)
  int my[WPT];
#pragma unroll
  for (int i = 0; i < WPT; ++i) {
    int j = s + t + i * BKN;
    my[i] = (j < e) ? ebuf[j] : -1;  // entries < 2^26, -1 is a safe sentinel
  }

  cnt[t] = 0;
  __syncthreads();
#pragma unroll
  for (int i = 0; i < WPT; ++i)
    if (my[i] >= 0) atomicAdd(&cnt[(my[i] >> 17) & (BKN - 1)], 1);
  __syncthreads();

  // block exclusive scan over 512 (1 per thread, 8 waves)
  int v = cnt[t];
  int lane = t & 63, w = t >> 6;
  int inc = v;
#pragma unroll
  for (int o = 1; o < 64; o <<= 1) {
    int u = __shfl_up(inc, o, 64);
    if (lane >= o) inc += u;
  }
  if (lane == 63) wsum[w] = inc;
  __syncthreads();
  if (t < 8) {
    int s0 = wsum[t], incw = s0;
#pragma unroll
    for (int o = 1; o < 8; o <<= 1) {
      int u = __shfl_up(incw, o, 64);
      if (t >= o) incw += u;
    }
    wsum[t] = incw - s0;
  }
  __syncthreads();
  int ex = wsum[w] + inc - v;
  int node = (b << BKSH) + t;
  if (node < N) rowse[node] = make_int2(s + ex, v);
  __syncthreads();
  cnt[t] = ex;  // seed scatter cursor with exclusive prefix
  __syncthreads();

  // in-LDS node-sort: atomic result is the final position in the window
#pragma unroll
  for (int i = 0; i < WPT; ++i) {
    if (my[i] >= 0) {
      int nl = (my[i] >> 17) & (BKN - 1);
      int p = atomicAdd(&cnt[nl], 1);
      sbuf[p] = my[i] & 0x1FFFF;
    }
  }
  __syncthreads();

  // coalesced flush
  for (int j = t; j < n; j += BKN) col[s + j] = sbuf[j];
}

// One wave per node on bf16 z rows (128B). The whole adjacency (deg <= 64,
// ~always for Poisson(12.5)) is loaded as ONE coalesced col line before the
// loop; per-iteration edge indices come from __shfl (VALU) instead of a
// global col load -> the col->z two-deep latency chain becomes shfl->z.
// The edge loop has a wave-UNIFORM trip count (kb < c, c uniform) with
// predicated accumulates: all 64 lanes stay active at every __shfl, so every
// shfl source lane is live (divergent-exit shfl is UB on gfx950 -- R6 bug).
// y row prefetched before the loop. fp32 accumulate, 3-round cross-oct
// shuffle reduce; epilogue: out = relu(y + mean) (8 lanes x 32B, full row).
__global__ __launch_bounds__(256) void gather_final(
    const unsigned short* __restrict__ zb,
    const int2* __restrict__ rowse,
    const int* __restrict__ col,
    const float* __restrict__ yb,
    float* __restrict__ out, int N) {
  int gid = blockIdx.x * 256 + threadIdx.x;
  int node = gid >> 6;
  if (node >= N) return;
  int lane = threadIdx.x & 63;
  int o = lane >> 3, d = lane & 7;
  int2 se = rowse[node];
  int s = se.x, c = se.y;

  long long ro = (long long)node * 64 + d * 8;
  float4 y0, y1;
  if (o == 0) {  // prefetch: independent of the edge loop
    y0 = *(const float4*)&yb[ro];
    y1 = *(const float4*)&yb[ro + 4];
  }

  float a[8] = {0.f, 0.f, 0.f, 0.f, 0.f, 0.f, 0.f, 0.f};
  float b2[8] = {0.f, 0.f, 0.f, 0.f, 0.f, 0.f, 0.f, 0.f};
  if (c > 0 && c <= 64) {
    int colv = col[s + min(lane, c - 1)];  // one coalesced line
    for (int kb = 0; kb < c; kb += 16) {   // UNIFORM trip count: c wave-uniform
      int k0 = kb + o;
      int k1 = k0 + 8;
      bool p0 = k0 < c, p1 = k1 < c;
      int c0 = __shfl(colv, p0 ? k0 : 0, 64);  // all lanes active; src valid
      int c1 = __shfl(colv, p1 ? k1 : 0, 64);
      short8 v0 = *(const short8*)&zb[(long long)c0 * 64 + d * 8];
      short8 v1 = *(const short8*)&zb[(long long)c1 * 64 + d * 8];
      if (p0) add8(a, v0);
      if (p1) add8(b2, v1);
    }
  } else if (c > 64) {  // rare fallback: deg > 64
    int e = s + c;
    for (int j = s + o; j < e; j += 16) {
      int c0 = col[j];
      bool h2 = (j + 8) < e;
      int c1 = h2 ? col[j + 8] : c0;
      short8 v0 = *(const short8*)&zb[(long long)c0 * 64 + d * 8];
      short8 v1 = *(const short8*)&zb[(long long)c1 * 64 + d * 8];
      add8(a, v0);
      if (h2) add8(b2, v1);
    }
  }
#pragma unroll
  for (int k = 0; k < 8; ++k) a[k] += b2[k];

#pragma unroll
  for (int m = 8; m <= 32; m <<= 1) {
#pragma unroll
    for (int k = 0; k < 8; ++k) a[k] += __shfl_xor(a[k], m, 64);
  }

  if (o == 0) {
    float inv = 1.0f / fmaxf((float)c, 1.0f);
    float4 r0, r1;
    r0.x = fmaxf(y0.x + a[0] * inv, 0.f);
    r0.y = fmaxf(y0.y + a[1] * inv, 0.f);
    r0.z = fmaxf(y0.z + a[2] * inv, 0.f);
    r0.w = fmaxf(y0.w + a[3] * inv, 0.f);
    r1.x = fmaxf(y1.x + a[4] * inv, 0.f);
    r1.y = fmaxf(y1.y + a[5] * inv, 0.f);
    r1.z = fmaxf(y1.z + a[6] * inv, 0.f);
    r1.w = fmaxf(y1.w + a[7] * inv, 0.f);
    *(float4*)&out[ro] = r0;
    *(float4*)&out[ro + 4] = r1;
  }
}

extern "C" void kernel_launch(void* const* d_in, const int* in_sizes, int n_in,
                              void* d_out, int out_size, void* d_ws, size_t ws_size,
                              hipStream_t stream) {
  const float* x      = (const float*)d_in[0];
  const int*   eidx   = (const int*)d_in[1];
  const float* Wself  = (const float*)d_in[2];
  const float* bself  = (const float*)d_in[3];
  const float* Wneigh = (const float*)d_in[4];
  float* out = (float*)d_out;

  const int N = in_sizes[0] / 64;
  const int E = in_sizes[1] / 2;
  const int* src = eidx;      // edge_index row 0
  const int* dst = eidx + E;  // edge_index row 1
  const int NB = (N + BKN - 1) / BKN;  // 196 buckets of 512 nodes

  // ws layout: yb fp32[N*64] | zb bf16[N*64] | cursor[256] | rowse int2[N]
  //            | ebuf[NB*CAPE] | col[NB*CAPE]   (~51 MB)
  float* yb = (float*)d_ws;
  unsigned short* zb = (unsigned short*)(yb + (size_t)N * 64);
  int* cursor = (int*)(zb + (size_t)N * 64);
  int2* rowse = (int2*)(cursor + NBMAX);
  int* ebuf   = (int*)(rowse + N);
  int* col    = ebuf + (size_t)NB * CAPE;

  hipMemsetAsync(cursor, 0, NBMAX * sizeof(int), stream);

  const int SCB = (E + CHUNK - 1) / CHUNK;  // 306 scatter blocks
  const int GB = (N + 63) / 64;             // 1563 GEMM blocks
  k1_main<<<SCB + GB, 256, 0, stream>>>(x, Wself, bself, Wneigh, yb, zb,
                                        src, dst, cursor, ebuf, E, N, NB, SCB);
  sb_csr<<<NB, BKN, 0, stream>>>(cursor, ebuf, col, rowse, N);
  gather_final<<<(int)(((long long)N * 64 + 255) / 256), 256, 0, stream>>>(
      zb, rowse, col, yb, out, N);
}